// Round 2
// baseline (666.647 us; speedup 1.0000x reference)
//
#include <hip/hip_runtime.h>
#include <hip/hip_bf16.h>

#define N_FEAT 128     // D_FEAT == UNITS == 128
#define EPT 8          // edges per thread in partition passes
#define CHUNK 2048     // 256 threads * EPT
#define BSHIFT 8       // bucket = node >> 8  (bucket range = 256 nodes)
#define MAXRANGE 256
#define CAP 8192       // per-bucket slot capacity (expected 4096 +- 64; 60-sigma margin)
#define PSTR 132       // pooled f32 LDS row stride in dwords (128+4: kills read conflicts)
#define ELCAP 2048     // staged edges per 16-node block (mean 256, 5-sigma ~336)

typedef short bf16x8 __attribute__((ext_vector_type(8)));
typedef float f32x4  __attribute__((ext_vector_type(4)));

__device__ __forceinline__ unsigned short f2bf_rtne(float f) {
    unsigned u = __float_as_uint(f);
    u += 0x7fffu + ((u >> 16) & 1u);
    return (unsigned short)(u >> 16);
}
__device__ __forceinline__ float bf2f(unsigned short h) {
    return __uint_as_float((unsigned)h << 16);
}

// ---------------------------------------------------------------------------
// K1: scatter into fixed-capacity buckets (R0-proven srcB path restored —
// R11's 800k scattered global atomicAdd(degS) was the likely +15us).
// ---------------------------------------------------------------------------
__global__ __launch_bounds__(256) void scatter_kernel(const int* __restrict__ source,
                                                      const int* __restrict__ target,
                                                      int* __restrict__ curT,
                                                      int* __restrict__ curS,
                                                      unsigned int* __restrict__ pairsT,
                                                      unsigned char* __restrict__ srcB,
                                                      int E, int NB) {
    __shared__ unsigned int   lds_pairs[CHUNK];    // 8 KB
    __shared__ unsigned short lds_sp[CHUNK];       // 4 KB (low16 of s)
    __shared__ int ct[MAXRANGE], cs[MAXRANGE];
    __shared__ int st[MAXRANGE], ss[MAXRANGE];
    __shared__ int gt[MAXRANGE], gs[MAXRANGE];
    int tid = threadIdx.x, b = blockIdx.x;
    int base = b * CHUNK;
    int cnt = E - base; if (cnt > CHUNK) cnt = CHUNK;

    int rs[EPT], rt[EPT];
    ct[tid] = 0; cs[tid] = 0;
    __syncthreads();
    #pragma unroll
    for (int j = 0; j < EPT; ++j) {
        int e = base + j * 256 + tid;
        if (e < E) {
            int s = source[e], t = target[e];
            rs[j] = s; rt[j] = t;
            atomicAdd(&ct[t >> BSHIFT], 1);
            atomicAdd(&cs[s >> BSHIFT], 1);
        }
    }
    __syncthreads();
    int vt = ct[tid], vs = cs[tid];
    st[tid] = vt; ss[tid] = vs;
    __syncthreads();
    #pragma unroll
    for (int off = 1; off < 256; off <<= 1) {
        int t1 = (tid >= off) ? st[tid - off] : 0;
        int t2 = (tid >= off) ? ss[tid - off] : 0;
        __syncthreads();
        st[tid] += t1; ss[tid] += t2;
        __syncthreads();
    }
    int et = st[tid] - vt, es = ss[tid] - vs;
    int gT = 0, gS = 0;
    if (tid < NB) {
        if (vt) gT = atomicAdd(&curT[tid], vt);
        if (vs) gS = atomicAdd(&curS[tid], vs);
    }
    __syncthreads();
    st[tid] = et; ss[tid] = es;
    ct[tid] = et; cs[tid] = es;
    gt[tid] = gT; gs[tid] = gS;
    __syncthreads();
    #pragma unroll
    for (int j = 0; j < EPT; ++j) {
        int e = base + j * 256 + tid;
        if (e < E) {
            int s = rs[j], t = rt[j];
            int k = t >> BSHIFT;
            int p = atomicAdd(&ct[k], 1);
            lds_pairs[p] = (unsigned)s | ((unsigned)t << 16);
            int k2 = s >> BSHIFT;
            int p2 = atomicAdd(&cs[k2], 1);
            lds_sp[p2] = (unsigned short)s;
        }
    }
    __syncthreads();
    for (int i = tid; i < cnt; i += 256) {
        unsigned w = lds_pairs[i];
        int k = w >> 24;
        pairsT[(size_t)k * CAP + gt[k] + (i - st[k])] = w;
        unsigned short sp = lds_sp[i];
        int k2 = sp >> 8;
        srcB[(size_t)k2 * CAP + gs[k2] + (i - ss[k2])] = (unsigned char)sp;
    }
}

// ---------------------------------------------------------------------------
// K2: fused prep (R0-proven). One change: elist entries now pack the local
// target row in bits 16..23 so K3 can process edges edge-parallel.
// ---------------------------------------------------------------------------
__global__ __launch_bounds__(256) void prep_kernel(const unsigned char* __restrict__ srcB,
                                                   const unsigned int* __restrict__ pairsT,
                                                   const int* __restrict__ curT,
                                                   const int* __restrict__ curS,
                                                   const float* __restrict__ x,
                                                   const float* __restrict__ W,
                                                   unsigned short* __restrict__ xb,
                                                   int2* __restrict__ offs,
                                                   int* __restrict__ elist,
                                                   float* __restrict__ ri,
                                                   unsigned short* __restrict__ Whi,
                                                   unsigned short* __restrict__ Wlo,
                                                   int N, int NB) {
    __shared__ int hist[MAXRANGE];
    __shared__ int sb[MAXRANGE];
    __shared__ int excl[MAXRANGE];
    __shared__ int cur[MAXRANGE];
    __shared__ float so_l[MAXRANGE];
    int tid = threadIdx.x, b = blockIdx.x;

    if (b < NB) {
        hist[tid] = 0;
        __syncthreads();
        int cnt = curS[b];
        size_t base = (size_t)b * CAP;
        for (int i = tid; i < cnt; i += 256)
            atomicAdd(&hist[srcB[base + i]], 1);
        __syncthreads();
        {
            int d = hist[tid]; if (d < 1) d = 1;
            so_l[tid] = rsqrtf((float)d);
        }
        __syncthreads();
        int row0 = b << BSHIFT;
        int nrows = N - row0; if (nrows > 256) nrows = 256;
        if (nrows <= 0) return;
        int nf4 = nrows * (N_FEAT / 4);
        const float4* xr = (const float4*)(x + (size_t)row0 * N_FEAT);
        ushort4* xo = (ushort4*)(xb + (size_t)row0 * N_FEAT);
        for (int i = tid; i < nf4; i += 256) {
            float s = so_l[i >> 5];
            float4 v = xr[i];
            xo[i] = make_ushort4(f2bf_rtne(s * v.x), f2bf_rtne(s * v.y),
                                 f2bf_rtne(s * v.z), f2bf_rtne(s * v.w));
        }
    } else if (b < 2 * NB) {
        int bb = b - NB;
        hist[tid] = 0; cur[tid] = 0;
        __syncthreads();
        int cnt = curT[bb];
        int gbase = bb * CAP;
        for (int i = tid; i < cnt; i += 256)
            atomicAdd(&hist[(pairsT[(size_t)gbase + i] >> 16) & 255], 1);
        __syncthreads();
        int deg = hist[tid];
        sb[tid] = deg;
        __syncthreads();
        #pragma unroll
        for (int off = 1; off < 256; off <<= 1) {
            int t = (tid >= off) ? sb[tid - off] : 0;
            __syncthreads();
            sb[tid] += t;
            __syncthreads();
        }
        excl[tid] = sb[tid] - deg;
        __syncthreads();
        int node = (bb << BSHIFT) + tid;
        if (node < N) {
            int st0 = gbase + excl[tid];
            offs[node] = make_int2(st0, st0 + deg);
            int d = deg; if (d < 1) d = 1;
            ri[node] = rsqrtf((float)d);
        }
        for (int i = tid; i < cnt; i += 256) {
            unsigned w = pairsT[(size_t)gbase + i];
            int tl = (w >> 16) & 255;
            int pos = atomicAdd(&cur[tl], 1);
            elist[gbase + excl[tl] + pos] = (int)(w & 0xFFFFu) | (tl << 16);
        }
    } else {
        int idx = (b - 2 * NB) * 256 + tid;
        int lane = idx & 63;
        int ks = (idx >> 6) & 3;
        int ct2 = idx >> 8;
        int n  = ct2 * 16 + (lane & 15);
        int k0 = ks * 32 + (lane >> 4) * 8;
        unsigned short h[8], l[8];
        #pragma unroll
        for (int j = 0; j < 8; ++j) {
            float w = W[(k0 + j) * N_FEAT + n];
            unsigned short hh = f2bf_rtne(w);
            h[j] = hh;
            l[j] = f2bf_rtne(w - bf2f(hh));
        }
        size_t off = (size_t)idx * 8;
        *(ushort4*)(Whi + off)     = make_ushort4(h[0], h[1], h[2], h[3]);
        *(ushort4*)(Whi + off + 4) = make_ushort4(h[4], h[5], h[6], h[7]);
        *(ushort4*)(Wlo + off)     = make_ushort4(l[0], l[1], l[2], l[3]);
        *(ushort4*)(Wlo + off + 4) = make_ushort4(l[4], l[5], l[6], l[7]);
    }
}

// Unpack one uint (2 bf16 feats) + LDS-atomic accumulate into pool row.
#define ACC2(u, p, o) { atomicAdd((p) + (o),     __uint_as_float((u) << 16)); \
                        atomicAdd((p) + (o) + 1, __uint_as_float((u) & 0xffff0000u)); }
#define EDGE_FLUSH(u, e) { float* p_ = pool + (((e) >> 16) & 15) * PSTR + k16 * 8; \
                           ACC2(u.x, p_, 0) ACC2(u.y, p_, 2) ACC2(u.z, p_, 4) ACC2(u.w, p_, 6) }

// ---------------------------------------------------------------------------
// K3: FUSED agg + gemm, R12 rewrite. The 16 nodes of a block live in one
// bucket, so their elist ranges are CONTIGUOUS: stage all ~256 edges into
// LDS with one coalesced pass (elist latency leaves the chain), then
// process edge-parallel: quarter-wave q owns edge chunk, each lane gathers
// uint4 (16B = 8 feats), accumulates via ds_add_f32 into a 16x128 f32 pool
// (no register-carry dependency -> all gathers independent, deep MLP).
// MFMA fragments are built straight from the f32 pool; ri folded into the
// epilogue (GEMM is linear per row).
// ---------------------------------------------------------------------------
__global__ __launch_bounds__(256) void agg_gemm_kernel(const unsigned short* __restrict__ xb,
                                                       const int* __restrict__ elist,
                                                       const int2* __restrict__ offs,
                                                       const float* __restrict__ ri,
                                                       const unsigned short* __restrict__ Whi,
                                                       const unsigned short* __restrict__ Wlo,
                                                       const float* __restrict__ bias,
                                                       float* __restrict__ out,
                                                       int N) {
    __shared__ float pool[16 * PSTR];   // 8.25 KB f32 pooled tile
    __shared__ int   el[ELCAP];         // 8 KB staged edges
    __shared__ float ril[16];
    int tid  = threadIdx.x;
    int wave = tid >> 6, lane = tid & 63;
    int quad = lane >> 4, k16 = lane & 15;
    int rowbase = blockIdx.x * 16;
    const uint4* xr = (const uint4*)xb;  // 16 granules per 128-feat row

    // ---- init: zero pool, stash ri, stage the block's contiguous edges ----
    for (int i = tid; i < 16 * PSTR; i += 256) pool[i] = 0.f;
    if (tid < 16) {
        int r = rowbase + tid;
        ril[tid] = (r < N) ? ri[r] : 0.f;
    }
    int lastrow = rowbase + 15; if (lastrow > N - 1) lastrow = N - 1;
    int start = offs[rowbase].x;
    int end   = offs[lastrow].y;
    int cnt   = end - start;
    int stg   = cnt < ELCAP ? cnt : ELCAP;
    for (int i = tid; i < stg; i += 256) el[i] = elist[start + i];
    __syncthreads();

    // ---- phase 1: edge-parallel gather + ds_add_f32 accumulate ----
    int qw    = wave * 4 + quad;           // quarter-wave id 0..15
    int chunk = (cnt + 15) >> 4;
    int jb = qw * chunk;
    int je = jb + chunk; if (je > cnt) je = cnt;
    int jm = je < stg ? je : stg;          // staged portion (all, in practice)
    int j = jb;
    for (; j + 4 <= jm; j += 4) {          // 4 independent gathers in flight
        int e0 = el[j], e1 = el[j + 1], e2 = el[j + 2], e3 = el[j + 3];
        uint4 u0 = xr[(e0 & 0xFFFF) * 16 + k16];
        uint4 u1 = xr[(e1 & 0xFFFF) * 16 + k16];
        uint4 u2 = xr[(e2 & 0xFFFF) * 16 + k16];
        uint4 u3 = xr[(e3 & 0xFFFF) * 16 + k16];
        EDGE_FLUSH(u0, e0) EDGE_FLUSH(u1, e1)
        EDGE_FLUSH(u2, e2) EDGE_FLUSH(u3, e3)
    }
    for (; j < jm; ++j) {
        int e = el[j];
        uint4 u = xr[(e & 0xFFFF) * 16 + k16];
        EDGE_FLUSH(u, e)
    }
    for (; j < je; ++j) {                  // overflow beyond ELCAP (rare/never)
        int e = elist[start + j];
        uint4 u = xr[(e & 0xFFFF) * 16 + k16];
        EDGE_FLUSH(u, e)
    }
    __syncthreads();

    // ---- phase 2: fragments from f32 pool + 16x128 MFMA tile ----
    bf16x8 Ahi[4], Alo[4];
    int m = k16;
    #pragma unroll
    for (int ks = 0; ks < 4; ++ks) {
        const float* p = pool + m * PSTR + ks * 32 + quad * 8;  // 8 consecutive feats
        f32x4 v0 = *(const f32x4*)p;
        f32x4 v1 = *(const f32x4*)(p + 4);
        float v[8] = { v0[0], v0[1], v0[2], v0[3], v1[0], v1[1], v1[2], v1[3] };
        #pragma unroll
        for (int t = 0; t < 8; ++t) {
            unsigned short h = f2bf_rtne(v[t]);
            Ahi[ks][t] = (short)h;
            Alo[ks][t] = (short)f2bf_rtne(v[t] - bf2f(h));
        }
    }
    const bf16x8* BH = (const bf16x8*)Whi;
    const bf16x8* BL = (const bf16x8*)Wlo;

    #pragma unroll
    for (int c = 0; c < 2; ++c) {
        int ct = wave * 2 + c;
        f32x4 acc = {0.f, 0.f, 0.f, 0.f};
        #pragma unroll
        for (int ks = 0; ks < 4; ++ks) {
            bf16x8 bh = BH[(ct * 4 + ks) * 64 + lane];
            bf16x8 bl = BL[(ct * 4 + ks) * 64 + lane];
            acc = __builtin_amdgcn_mfma_f32_16x16x32_bf16(Ahi[ks], bh, acc, 0, 0, 0);
            acc = __builtin_amdgcn_mfma_f32_16x16x32_bf16(Alo[ks], bh, acc, 0, 0, 0);
            acc = __builtin_amdgcn_mfma_f32_16x16x32_bf16(Ahi[ks], bl, acc, 0, 0, 0);
        }
        int colc = ct * 16 + m;
        float bv = bias[colc];
        #pragma unroll
        for (int reg = 0; reg < 4; ++reg) {
            int r = rowbase + quad * 4 + reg;
            if (r < N)
                out[(size_t)r * N_FEAT + colc] =
                    fmaxf(acc[reg] * ril[quad * 4 + reg] + bv, 0.f);
        }
    }
}

// ---------------------------------------------------------------------------
extern "C" void kernel_launch(void* const* d_in, const int* in_sizes, int n_in,
                              void* d_out, int out_size, void* d_ws, size_t ws_size,
                              hipStream_t stream) {
    const float* x      = (const float*)d_in[0];
    const int*   source = (const int*)d_in[1];
    const int*   target = (const int*)d_in[2];
    const float* W      = (const float*)d_in[3];
    const float* bias   = (const float*)d_in[4];
    float*       out    = (float*)d_out;

    const int N = in_sizes[0] / N_FEAT;   // 50000
    const int E = in_sizes[1];            // 800000

    const int NB   = (N + MAXRANGE - 1) >> BSHIFT;  // 196
    const int NBLK = (E + CHUNK - 1) / CHUNK;       // 391

    uintptr_t p = (uintptr_t)d_ws;
    auto carve = [&](size_t bytes) {
        p = (p + 255) & ~(uintptr_t)255;
        uintptr_t r = p;
        p += bytes;
        return (void*)r;
    };
    int*            curs    = (int*)carve((size_t)2 * NB * sizeof(int)); // curT|curS (memset)
    int*            curT    = curs;
    int*            curS    = curs + NB;
    unsigned int*   pairsT  = (unsigned int*)carve((size_t)NB * CAP * sizeof(unsigned int));
    int*            elist   = (int*)carve((size_t)NB * CAP * sizeof(int) + 256);
    unsigned char*  srcB    = (unsigned char*)carve((size_t)NB * CAP);
    float*          ri      = (float*)carve((size_t)N * sizeof(float));
    int2*           offs    = (int2*)carve((size_t)N * sizeof(int2));
    unsigned short* xb      = (unsigned short*)carve((size_t)N * N_FEAT * sizeof(unsigned short));
    unsigned short* Whi     = (unsigned short*)carve((size_t)N_FEAT * N_FEAT * sizeof(unsigned short));
    unsigned short* Wlo     = (unsigned short*)carve((size_t)N_FEAT * N_FEAT * sizeof(unsigned short));
    (void)ws_size; (void)n_in; (void)out_size;

    (void)hipMemsetAsync(curs, 0, (size_t)2 * NB * sizeof(int), stream);

    scatter_kernel<<<NBLK, 256, 0, stream>>>(source, target, curT, curS, pairsT, srcB, E, NB);
    prep_kernel<<<2 * NB + 8, 256, 0, stream>>>(srcB, pairsT, curT, curS, x, W,
                                                xb, offs, elist, ri, Whi, Wlo, N, NB);
    agg_gemm_kernel<<<(N + 15) / 16, 256, 0, stream>>>(xb, elist, offs, ri,
                                                       Whi, Wlo, bias, out, N);
}

// Round 3
// 157.024 us; speedup vs baseline: 4.2455x; 4.2455x over previous
//
#include <hip/hip_runtime.h>
#include <hip/hip_bf16.h>

#define N_FEAT 128     // D_FEAT == UNITS == 128
#define EPT 8          // edges per thread in partition passes
#define CHUNK 2048     // 256 threads * EPT
#define BSHIFT 8       // bucket = node >> 8  (bucket range = 256 nodes)
#define MAXRANGE 256
#define CAP 8192       // per-bucket slot capacity (expected 4096 +- 64; 60-sigma margin)
#define LSTR 66        // LDS row stride in dwords (=132 bf16) for the pooled tile
#define ELCAP 512      // staged edges per 16-node block (mean 256, sd 16 -> +16 sigma)

typedef short bf16x8 __attribute__((ext_vector_type(8)));
typedef float f32x4  __attribute__((ext_vector_type(4)));

__device__ __forceinline__ unsigned short f2bf_rtne(float f) {
    unsigned u = __float_as_uint(f);
    u += 0x7fffu + ((u >> 16) & 1u);
    return (unsigned short)(u >> 16);
}
__device__ __forceinline__ float bf2f(unsigned short h) {
    return __uint_as_float((unsigned)h << 16);
}

// ---------------------------------------------------------------------------
// K1: scatter into fixed-capacity buckets (R10-proven, verbatim).
// ---------------------------------------------------------------------------
__global__ __launch_bounds__(256) void scatter_kernel(const int* __restrict__ source,
                                                      const int* __restrict__ target,
                                                      int* __restrict__ curT,
                                                      int* __restrict__ curS,
                                                      unsigned int* __restrict__ pairsT,
                                                      unsigned char* __restrict__ srcB,
                                                      int E, int NB) {
    __shared__ unsigned int   lds_pairs[CHUNK];    // 8 KB
    __shared__ unsigned short lds_sp[CHUNK];       // 4 KB (low16 of s)
    __shared__ int ct[MAXRANGE], cs[MAXRANGE];
    __shared__ int st[MAXRANGE], ss[MAXRANGE];
    __shared__ int gt[MAXRANGE], gs[MAXRANGE];
    int tid = threadIdx.x, b = blockIdx.x;
    int base = b * CHUNK;
    int cnt = E - base; if (cnt > CHUNK) cnt = CHUNK;

    int rs[EPT], rt[EPT];
    ct[tid] = 0; cs[tid] = 0;
    __syncthreads();
    #pragma unroll
    for (int j = 0; j < EPT; ++j) {
        int e = base + j * 256 + tid;
        if (e < E) {
            int s = source[e], t = target[e];
            rs[j] = s; rt[j] = t;
            atomicAdd(&ct[t >> BSHIFT], 1);
            atomicAdd(&cs[s >> BSHIFT], 1);
        }
    }
    __syncthreads();
    int vt = ct[tid], vs = cs[tid];
    st[tid] = vt; ss[tid] = vs;
    __syncthreads();
    #pragma unroll
    for (int off = 1; off < 256; off <<= 1) {
        int t1 = (tid >= off) ? st[tid - off] : 0;
        int t2 = (tid >= off) ? ss[tid - off] : 0;
        __syncthreads();
        st[tid] += t1; ss[tid] += t2;
        __syncthreads();
    }
    int et = st[tid] - vt, es = ss[tid] - vs;
    int gT = 0, gS = 0;
    if (tid < NB) {
        if (vt) gT = atomicAdd(&curT[tid], vt);
        if (vs) gS = atomicAdd(&curS[tid], vs);
    }
    __syncthreads();
    st[tid] = et; ss[tid] = es;
    ct[tid] = et; cs[tid] = es;
    gt[tid] = gT; gs[tid] = gS;
    __syncthreads();
    #pragma unroll
    for (int j = 0; j < EPT; ++j) {
        int e = base + j * 256 + tid;
        if (e < E) {
            int s = rs[j], t = rt[j];
            int k = t >> BSHIFT;
            int p = atomicAdd(&ct[k], 1);
            lds_pairs[p] = (unsigned)s | ((unsigned)t << 16);
            int k2 = s >> BSHIFT;
            int p2 = atomicAdd(&cs[k2], 1);
            lds_sp[p2] = (unsigned short)s;
        }
    }
    __syncthreads();
    for (int i = tid; i < cnt; i += 256) {
        unsigned w = lds_pairs[i];
        int k = w >> 24;
        pairsT[(size_t)k * CAP + gt[k] + (i - st[k])] = w;
        unsigned short sp = lds_sp[i];
        int k2 = sp >> 8;
        srcB[(size_t)k2 * CAP + gs[k2] + (i - ss[k2])] = (unsigned char)sp;
    }
}

// ---------------------------------------------------------------------------
// K2: fused prep (R10-proven, verbatim).
// ---------------------------------------------------------------------------
__global__ __launch_bounds__(256) void prep_kernel(const unsigned char* __restrict__ srcB,
                                                   const unsigned int* __restrict__ pairsT,
                                                   const int* __restrict__ curT,
                                                   const int* __restrict__ curS,
                                                   const float* __restrict__ x,
                                                   const float* __restrict__ W,
                                                   unsigned short* __restrict__ xb,
                                                   int2* __restrict__ offs,
                                                   int* __restrict__ elist,
                                                   float* __restrict__ ri,
                                                   unsigned short* __restrict__ Whi,
                                                   unsigned short* __restrict__ Wlo,
                                                   int N, int NB) {
    __shared__ int hist[MAXRANGE];
    __shared__ int sb[MAXRANGE];
    __shared__ int excl[MAXRANGE];
    __shared__ int cur[MAXRANGE];
    __shared__ float so_l[MAXRANGE];
    int tid = threadIdx.x, b = blockIdx.x;

    if (b < NB) {
        hist[tid] = 0;
        __syncthreads();
        int cnt = curS[b];
        size_t base = (size_t)b * CAP;
        for (int i = tid; i < cnt; i += 256)
            atomicAdd(&hist[srcB[base + i]], 1);
        __syncthreads();
        {
            int d = hist[tid]; if (d < 1) d = 1;
            so_l[tid] = rsqrtf((float)d);
        }
        __syncthreads();
        int row0 = b << BSHIFT;
        int nrows = N - row0; if (nrows > 256) nrows = 256;
        if (nrows <= 0) return;
        int nf4 = nrows * (N_FEAT / 4);
        const float4* xr = (const float4*)(x + (size_t)row0 * N_FEAT);
        ushort4* xo = (ushort4*)(xb + (size_t)row0 * N_FEAT);
        for (int i = tid; i < nf4; i += 256) {
            float s = so_l[i >> 5];
            float4 v = xr[i];
            xo[i] = make_ushort4(f2bf_rtne(s * v.x), f2bf_rtne(s * v.y),
                                 f2bf_rtne(s * v.z), f2bf_rtne(s * v.w));
        }
    } else if (b < 2 * NB) {
        int bb = b - NB;
        hist[tid] = 0; cur[tid] = 0;
        __syncthreads();
        int cnt = curT[bb];
        int gbase = bb * CAP;
        for (int i = tid; i < cnt; i += 256)
            atomicAdd(&hist[(pairsT[(size_t)gbase + i] >> 16) & 255], 1);
        __syncthreads();
        int deg = hist[tid];
        sb[tid] = deg;
        __syncthreads();
        #pragma unroll
        for (int off = 1; off < 256; off <<= 1) {
            int t = (tid >= off) ? sb[tid - off] : 0;
            __syncthreads();
            sb[tid] += t;
            __syncthreads();
        }
        excl[tid] = sb[tid] - deg;
        __syncthreads();
        int node = (bb << BSHIFT) + tid;
        if (node < N) {
            int st0 = gbase + excl[tid];
            offs[node] = make_int2(st0, st0 + deg);
            int d = deg; if (d < 1) d = 1;
            ri[node] = rsqrtf((float)d);
        }
        for (int i = tid; i < cnt; i += 256) {
            unsigned w = pairsT[(size_t)gbase + i];
            int tl = (w >> 16) & 255;
            int pos = atomicAdd(&cur[tl], 1);
            elist[gbase + excl[tl] + pos] = (int)(w & 0xFFFFu);
        }
    } else {
        int idx = (b - 2 * NB) * 256 + tid;
        int lane = idx & 63;
        int ks = (idx >> 6) & 3;
        int ct2 = idx >> 8;
        int n  = ct2 * 16 + (lane & 15);
        int k0 = ks * 32 + (lane >> 4) * 8;
        unsigned short h[8], l[8];
        #pragma unroll
        for (int j = 0; j < 8; ++j) {
            float w = W[(k0 + j) * N_FEAT + n];
            unsigned short hh = f2bf_rtne(w);
            h[j] = hh;
            l[j] = f2bf_rtne(w - bf2f(hh));
        }
        size_t off = (size_t)idx * 8;
        *(ushort4*)(Whi + off)     = make_ushort4(h[0], h[1], h[2], h[3]);
        *(ushort4*)(Whi + off + 4) = make_ushort4(h[4], h[5], h[6], h[7]);
        *(ushort4*)(Wlo + off)     = make_ushort4(l[0], l[1], l[2], l[3]);
        *(ushort4*)(Wlo + off + 4) = make_ushort4(l[4], l[5], l[6], l[7]);
    }
}

// ---------------------------------------------------------------------------
// K3: FUSED agg + gemm, R13. Quad-per-node gather: the block's 16 nodes
// share one bucket so their elist ranges are CONTIGUOUS -> staged to LDS
// with one coalesced pass. Quarter-wave q of wave w owns node w*4+q; lane
// (q,k16) gathers uint4 granule k16 (8 feats) of each source row -- one
// quad's 16 lanes fetch exactly one 256B row coalesced. Unroll-8 keeps 8
// independent uint4 loads in flight per lane feeding 8 private f32
// accumulators: NO atomics, NO shfl, NO cross-iteration dependency. Lane
// ends holding feats [8*k16,8*k16+8) of its node = exactly the hi/lo LDS
// layout phase 2 consumes. Phase 2 (MFMA) unchanged from R10.
// ---------------------------------------------------------------------------
__global__ __launch_bounds__(256) void agg_gemm_kernel(const unsigned short* __restrict__ xb,
                                                       const int* __restrict__ elist,
                                                       const int2* __restrict__ offs,
                                                       const float* __restrict__ ri,
                                                       const unsigned short* __restrict__ Whi,
                                                       const unsigned short* __restrict__ Wlo,
                                                       const float* __restrict__ bias,
                                                       float* __restrict__ out,
                                                       int N) {
    __shared__ unsigned int hi_l[16 * LSTR];   // 4.2 KB
    __shared__ unsigned int lo_l[16 * LSTR];   // 4.2 KB
    __shared__ int el[ELCAP];                  // 2 KB staged edge sources
    int tid  = threadIdx.x;
    int wave = tid >> 6, lane = tid & 63;
    int quad = lane >> 4, k16 = lane & 15;
    int rowbase = blockIdx.x * 16;
    const uint4* xr = (const uint4*)xb;        // 16 granules per 128-feat row

    // ---- stage the block's contiguous edge range (coalesced, once) ----
    int lastrow = rowbase + 15; if (lastrow > N - 1) lastrow = N - 1;
    int blk0 = offs[rowbase].x;
    int cnt  = offs[lastrow].y - blk0;
    int stg  = cnt < ELCAP ? cnt : ELCAP;
    for (int i = tid; i < stg; i += 256) el[i] = elist[blk0 + i];
    __syncthreads();

    // ---- phase 1: quad-per-node gather-accumulate ----
    int rl   = wave * 4 + quad;                // local row 0..15
    int node = rowbase + rl;
    int ls = 0, le = 0;
    float rr = 0.f;
    if (node < N) {
        int2 oe = offs[node];                  // same addr across quad: broadcast
        ls = oe.x - blk0; le = oe.y - blk0;
        rr = ri[node];
    }
    float acc[8] = {0.f, 0.f, 0.f, 0.f, 0.f, 0.f, 0.f, 0.f};
    for (int j = ls; j < le; j += 8) {
        uint4 u[8];
        #pragma unroll
        for (int t = 0; t < 8; ++t) {
            int idx = j + t;
            if (idx < le) {
                int e = (idx < stg) ? el[idx] : elist[blk0 + idx];
                u[t] = xr[(size_t)e * 16 + k16];
            }
        }
        #pragma unroll
        for (int t = 0; t < 8; ++t) {
            if (j + t < le) {
                acc[0] += __uint_as_float(u[t].x << 16);
                acc[1] += __uint_as_float(u[t].x & 0xffff0000u);
                acc[2] += __uint_as_float(u[t].y << 16);
                acc[3] += __uint_as_float(u[t].y & 0xffff0000u);
                acc[4] += __uint_as_float(u[t].z << 16);
                acc[5] += __uint_as_float(u[t].z & 0xffff0000u);
                acc[6] += __uint_as_float(u[t].w << 16);
                acc[7] += __uint_as_float(u[t].w & 0xffff0000u);
            }
        }
    }
    // ---- scale + hi/lo bf16 split; lane writes 4 dwords of its row ----
    {
        unsigned int* hd = hi_l + rl * LSTR + 4 * k16;
        unsigned int* ld = lo_l + rl * LSTR + 4 * k16;
        #pragma unroll
        for (int d = 0; d < 4; ++d) {
            float v0 = acc[2 * d] * rr;
            float v1 = acc[2 * d + 1] * rr;
            unsigned short h0 = f2bf_rtne(v0), h1 = f2bf_rtne(v1);
            unsigned short l0 = f2bf_rtne(v0 - bf2f(h0));
            unsigned short l1 = f2bf_rtne(v1 - bf2f(h1));
            hd[d] = (unsigned)h0 | ((unsigned)h1 << 16);
            ld[d] = (unsigned)l0 | ((unsigned)l1 << 16);
        }
    }
    __syncthreads();

    // ---- phase 2: 16x128 MFMA tile (unchanged from R10) ----
    bf16x8 Ahi[4], Alo[4];
    int m = k16;
    #pragma unroll
    for (int ks = 0; ks < 4; ++ks) {
        int a = m * LSTR + ks * 16 + quad * 4;
        Ahi[ks] = *(const bf16x8*)(hi_l + a);
        Alo[ks] = *(const bf16x8*)(lo_l + a);
    }
    const bf16x8* BH = (const bf16x8*)Whi;
    const bf16x8* BL = (const bf16x8*)Wlo;

    #pragma unroll
    for (int c = 0; c < 2; ++c) {
        int ct = wave * 2 + c;
        f32x4 acc2 = {0.f, 0.f, 0.f, 0.f};
        #pragma unroll
        for (int ks = 0; ks < 4; ++ks) {
            bf16x8 bh = BH[(ct * 4 + ks) * 64 + lane];
            bf16x8 bl = BL[(ct * 4 + ks) * 64 + lane];
            acc2 = __builtin_amdgcn_mfma_f32_16x16x32_bf16(Ahi[ks], bh, acc2, 0, 0, 0);
            acc2 = __builtin_amdgcn_mfma_f32_16x16x32_bf16(Alo[ks], bh, acc2, 0, 0, 0);
            acc2 = __builtin_amdgcn_mfma_f32_16x16x32_bf16(Ahi[ks], bl, acc2, 0, 0, 0);
        }
        int colc = ct * 16 + m;
        float bv = bias[colc];
        #pragma unroll
        for (int reg = 0; reg < 4; ++reg) {
            int r = rowbase + quad * 4 + reg;
            if (r < N)
                out[(size_t)r * N_FEAT + colc] = fmaxf(acc2[reg] + bv, 0.f);
        }
    }
}

// ---------------------------------------------------------------------------
extern "C" void kernel_launch(void* const* d_in, const int* in_sizes, int n_in,
                              void* d_out, int out_size, void* d_ws, size_t ws_size,
                              hipStream_t stream) {
    const float* x      = (const float*)d_in[0];
    const int*   source = (const int*)d_in[1];
    const int*   target = (const int*)d_in[2];
    const float* W      = (const float*)d_in[3];
    const float* bias   = (const float*)d_in[4];
    float*       out    = (float*)d_out;

    const int N = in_sizes[0] / N_FEAT;   // 50000
    const int E = in_sizes[1];            // 800000

    const int NB   = (N + MAXRANGE - 1) >> BSHIFT;  // 196
    const int NBLK = (E + CHUNK - 1) / CHUNK;       // 391

    uintptr_t p = (uintptr_t)d_ws;
    auto carve = [&](size_t bytes) {
        p = (p + 255) & ~(uintptr_t)255;
        uintptr_t r = p;
        p += bytes;
        return (void*)r;
    };
    int*            curs    = (int*)carve((size_t)2 * NB * sizeof(int)); // curT|curS (memset)
    int*            curT    = curs;
    int*            curS    = curs + NB;
    unsigned int*   pairsT  = (unsigned int*)carve((size_t)NB * CAP * sizeof(unsigned int));
    int*            elist   = (int*)carve((size_t)NB * CAP * sizeof(int));
    unsigned char*  srcB    = (unsigned char*)carve((size_t)NB * CAP);
    float*          ri      = (float*)carve((size_t)N * sizeof(float));
    int2*           offs    = (int2*)carve((size_t)N * sizeof(int2));
    unsigned short* xb      = (unsigned short*)carve((size_t)N * N_FEAT * sizeof(unsigned short));
    unsigned short* Whi     = (unsigned short*)carve((size_t)N_FEAT * N_FEAT * sizeof(unsigned short));
    unsigned short* Wlo     = (unsigned short*)carve((size_t)N_FEAT * N_FEAT * sizeof(unsigned short));
    (void)ws_size; (void)n_in; (void)out_size;

    (void)hipMemsetAsync(curs, 0, (size_t)2 * NB * sizeof(int), stream);

    scatter_kernel<<<NBLK, 256, 0, stream>>>(source, target, curT, curS, pairsT, srcB, E, NB);
    prep_kernel<<<2 * NB + 8, 256, 0, stream>>>(srcB, pairsT, curT, curS, x, W,
                                                xb, offs, elist, ri, Whi, Wlo, N, NB);
    agg_gemm_kernel<<<(N + 15) / 16, 256, 0, stream>>>(xb, elist, offs, ri,
                                                       Whi, Wlo, bias, out, N);
}